// Round 2
// baseline (442.062 us; speedup 1.0000x reference)
//
#include <hip/hip_runtime.h>

#define BS   64
#define NQ   3000
#define NC   256
#define FH   100
#define FW   100
#define TOPK 1500

// ---------------- Kernel A: scores[b,q] = max_c class[b,q,c] ----------------
// 16 lanes per row, 8 rows per wave -> 8 independent float4 loads per lane.
__global__ __launch_bounds__(256) void scores_kernel(const float4* __restrict__ cls,
                                                     float* __restrict__ scores) {
    const int tid   = threadIdx.x;
    const int lane  = tid & 63;
    const int wave  = tid >> 6;
    const int sub   = lane & 15;   // position within row (16 float4 stride)
    const int rq    = lane >> 4;   // 0..3: which row of the quad
    // 32 rows per block (4 waves x 8 rows). Grid sized exactly: no bounds check.
    const int row0 = blockIdx.x * 32 + wave * 8 + rq;      // rows row0 and row0+4
    const float4* p  = cls + (size_t)row0 * (NC / 4) + sub;
    const float4* p2 = p + 4 * (NC / 4);
    float4 a = p[0],  b = p[16],  c = p[32],  d = p[48];
    float4 e = p2[0], f = p2[16], g = p2[32], h = p2[48];
    float m1 = fmaxf(fmaxf(fmaxf(a.x, a.y), fmaxf(a.z, a.w)),
                     fmaxf(fmaxf(b.x, b.y), fmaxf(b.z, b.w)));
    m1 = fmaxf(m1, fmaxf(fmaxf(c.x, c.y), fmaxf(c.z, c.w)));
    m1 = fmaxf(m1, fmaxf(fmaxf(d.x, d.y), fmaxf(d.z, d.w)));
    float m2 = fmaxf(fmaxf(fmaxf(e.x, e.y), fmaxf(e.z, e.w)),
                     fmaxf(fmaxf(f.x, f.y), fmaxf(f.z, f.w)));
    m2 = fmaxf(m2, fmaxf(fmaxf(g.x, g.y), fmaxf(g.z, g.w)));
    m2 = fmaxf(m2, fmaxf(fmaxf(h.x, h.y), fmaxf(h.z, h.w)));
#pragma unroll
    for (int off = 8; off > 0; off >>= 1) {
        m1 = fmaxf(m1, __shfl_down(m1, off, 16));
        m2 = fmaxf(m2, __shfl_down(m2, off, 16));
    }
    if (sub == 0) {
        scores[row0]     = m1;
        scores[row0 + 4] = m2;
    }
}

// ---------------- Kernel B: per-batch top-k select + raster + mask ----------
#define NT 1024

__global__ __launch_bounds__(NT) void mask_kernel(const float4* __restrict__ coord,
                                                  const int* __restrict__ vfs,
                                                  const float* __restrict__ scores,
                                                  float* __restrict__ out) {
    __shared__ unsigned su[NQ];        // score bits (positive floats: uint order == float order)
    __shared__ int      eqlist[NQ];    // indices with su == v (worst case all)
    __shared__ unsigned rects[TOPK];   // packed h0|h1<<7|w0<<14|w1<<21
    __shared__ unsigned covh[FH * 8];  // per-(row,word,half) column bits
    __shared__ int      hist[256];
    __shared__ int      s_selbin, s_K, s_ecnt, s_nrect;

    const int b   = blockIdx.x;
    const int tid = threadIdx.x;

    for (int q = tid; q < NQ; q += NT)
        su[q] = __float_as_uint(scores[b * NQ + q]);
    if (tid == 0) { s_ecnt = 0; s_nrect = 0; }
    __syncthreads();

    // ---- byte-wise radix descent: v = TOPK-th largest value (exact bits) ----
    unsigned prefix = 0, pmask = 0;
    int K = TOPK;
#pragma unroll
    for (int p = 0; p < 4; ++p) {
        const int shift = 24 - 8 * p;
        for (int i = tid; i < 256; i += NT) hist[i] = 0;
        __syncthreads();
        for (int q = tid; q < NQ; q += NT) {
            unsigned u = su[q];
            if ((u & pmask) == prefix)
                atomicAdd(&hist[(u >> shift) & 0xFF], 1);
        }
        __syncthreads();
        if (tid == 0) {
            int cum = 0, b2 = 255;
            for (; b2 > 0; --b2) {
                int c = hist[b2];
                if (cum + c >= K) break;
                cum += c;
            }
            s_selbin = b2;
            s_K      = K - cum;
        }
        __syncthreads();
        prefix |= ((unsigned)s_selbin) << shift;
        pmask  |= (0xFFu << shift);
        K = s_K;
        __syncthreads();
    }
    const unsigned v      = prefix;  // exact bits of k-th largest
    const int      e_take = K;       // how many su==v to take (smallest indices first)

    const float s0 = (float)vfs[2 * b];      // reference scales x by vfs[:,0]
    const float s1 = (float)vfs[2 * b + 1];  // and y by vfs[:,1] (replicate quirk)

    // ---- selection: su > v always in; su == v gathered for stable tie-break ----
    for (int q = tid; q < NQ; q += NT) {
        unsigned u = su[q];
        if (u > v) {
            float4 c4 = coord[(size_t)b * NQ + q];
            float x1 = c4.x - 0.5f * c4.z, y1 = c4.y - 0.5f * c4.w;
            float x2 = c4.x + 0.5f * c4.z, y2 = c4.y + 0.5f * c4.w;
            int lx = (int)floorf(x1 * s0), ly = (int)floorf(y1 * s1);
            int rx = (int)floorf(x2 * s0), ry = (int)floorf(y2 * s1);
            int h0 = ly > 0 ? ly : 0, h1 = ry < FH ? ry : FH;
            int w0 = lx > 0 ? lx : 0, w1 = rx < FW ? rx : FW;
            if (h0 < h1 && w0 < w1) {
                int slot = atomicAdd(&s_nrect, 1);
                rects[slot] = (unsigned)h0 | ((unsigned)h1 << 7) |
                              ((unsigned)w0 << 14) | ((unsigned)w1 << 21);
            }
        } else if (u == v) {
            int i = atomicAdd(&s_ecnt, 1);
            eqlist[i] = q;
        }
    }
    __syncthreads();
    const int E = s_ecnt;
    for (int i = tid; i < E; i += NT) {
        int q = eqlist[i];
        int r = 0;
        for (int j = 0; j < E; ++j) r += (eqlist[j] < q) ? 1 : 0;
        if (r < e_take) {
            float4 c4 = coord[(size_t)b * NQ + q];
            float x1 = c4.x - 0.5f * c4.z, y1 = c4.y - 0.5f * c4.w;
            float x2 = c4.x + 0.5f * c4.z, y2 = c4.y + 0.5f * c4.w;
            int lx = (int)floorf(x1 * s0), ly = (int)floorf(y1 * s1);
            int rx = (int)floorf(x2 * s0), ry = (int)floorf(y2 * s1);
            int h0 = ly > 0 ? ly : 0, h1 = ry < FH ? ry : FH;
            int w0 = lx > 0 ? lx : 0, w1 = rx < FW ? rx : FW;
            if (h0 < h1 && w0 < w1) {
                int slot = atomicAdd(&s_nrect, 1);
                rects[slot] = (unsigned)h0 | ((unsigned)h1 << 7) |
                              ((unsigned)w0 << 14) | ((unsigned)w1 << 21);
            }
        }
    }
    __syncthreads();

    // ---- raster: thread owns (row h, word j, half); broadcast reads, no atomics ----
    const int nr = s_nrect;
    if (tid < FH * 8) {
        const int h    = tid >> 3;
        const int j    = (tid >> 1) & 3;
        const int half = tid & 1;
        unsigned acc = 0;
        for (int i = half; i < nr; i += 2) {
            unsigned r = rects[i];
            int h0 = r & 127, h1 = (r >> 7) & 127;
            if (h >= h0 && h < h1) {
                int w0 = (r >> 14) & 127, w1 = (r >> 21) & 127;
                int lo = w0 - 32 * j; lo = lo < 0 ? 0 : lo;
                int hi = w1 - 32 * j; hi = hi > 32 ? 32 : hi;
                if (hi > lo) {
                    unsigned top = (hi >= 32) ? 0xFFFFFFFFu : ((1u << hi) - 1u);
                    unsigned bot = (lo <= 0) ? 0u : ((1u << lo) - 1u);
                    acc |= top & ~bot;
                }
            }
        }
        covh[tid] = acc;
    }
    __syncthreads();

    // ---- emit mask fused with padding (recomputed from vfs) ----
    const int iv0 = vfs[2 * b], iv1 = vfs[2 * b + 1];
    for (int idx = tid; idx < FH * FW; idx += NT) {
        int h = idx / FW;
        int w = idx - h * FW;
        unsigned cw = covh[h * 8 + (w >> 5) * 2] | covh[h * 8 + (w >> 5) * 2 + 1];
        bool covered = (cw >> (w & 31)) & 1u;
        bool pad = (h >= iv0) || (w >= iv1);
        out[(size_t)b * (FH * FW) + idx] = (covered && !pad) ? 0.0f : -1e20f;
    }
}

extern "C" void kernel_launch(void* const* d_in, const int* in_sizes, int n_in,
                              void* d_out, int out_size, void* d_ws, size_t ws_size,
                              hipStream_t stream) {
    const float4* coord = (const float4*)d_in[0];  // (BS, NQ, 4) f32
    const float*  cls   = (const float*)d_in[1];   // (BS, NQ, NC) f32
    const int*    vfs   = (const int*)d_in[2];     // (BS, 2) i32
    // d_in[3] (padding_mask) ignored — recomputed from vfs.
    float* scores = (float*)d_ws;                  // BS*NQ floats
    float* out    = (float*)d_out;

    const int rows = BS * NQ;                      // 192000
    scores_kernel<<<rows / 32, 256, 0, stream>>>((const float4*)cls, scores);
    mask_kernel<<<BS, NT, 0, stream>>>(coord, vfs, scores, out);
}

// Round 3
// 316.385 us; speedup vs baseline: 1.3972x; 1.3972x over previous
//
#include <hip/hip_runtime.h>

#define BS   64
#define NQ   3000
#define NC   256
#define FH   100
#define FW   100
#define TOPK 1500

// ---------------- Kernel A: scores[b,q] = max_c class[b,q,c] ----------------
// One row (64 float4) per wave-iteration; 4 rows per wave for 4 outstanding
// loads. Lane l reads float4 l of each row (1 KB coalesced per instruction).
__global__ __launch_bounds__(256) void scores_kernel(const float4* __restrict__ cls,
                                                     float* __restrict__ scores) {
    const int tid  = threadIdx.x;
    const int lane = tid & 63;
    const int wave = tid >> 6;
    const int row0 = blockIdx.x * 16 + wave * 4;  // 16 rows per block, grid exact
    const float4* p = cls + (size_t)row0 * (NC / 4) + lane;
    float4 a = p[0], b = p[64], c = p[128], d = p[192];
    float m0 = fmaxf(fmaxf(a.x, a.y), fmaxf(a.z, a.w));
    float m1 = fmaxf(fmaxf(b.x, b.y), fmaxf(b.z, b.w));
    float m2 = fmaxf(fmaxf(c.x, c.y), fmaxf(c.z, c.w));
    float m3 = fmaxf(fmaxf(d.x, d.y), fmaxf(d.z, d.w));
#pragma unroll
    for (int off = 32; off > 0; off >>= 1) {
        m0 = fmaxf(m0, __shfl_xor(m0, off, 64));
        m1 = fmaxf(m1, __shfl_xor(m1, off, 64));
        m2 = fmaxf(m2, __shfl_xor(m2, off, 64));
        m3 = fmaxf(m3, __shfl_xor(m3, off, 64));
    }
    if (lane < 4) {
        float m = (lane == 0) ? m0 : (lane == 1) ? m1 : (lane == 2) ? m2 : m3;
        scores[row0 + lane] = m;
    }
}

// ---------------- Kernel B: per-batch top-k select + raster + mask ----------
#define NTM 512  // 8 waves

__global__ __launch_bounds__(NTM) void mask_kernel(const float4* __restrict__ coord,
                                                   const int* __restrict__ vfs,
                                                   const float* __restrict__ scores,
                                                   float* __restrict__ out) {
    __shared__ unsigned su[NQ];        // score bits (positive: uint order == float order)
    __shared__ int      hist[8][256];  // per-wave histograms
    __shared__ unsigned cov[FH * 4];   // 100 rows x 128-bit coverage
    __shared__ int      eqlist[NQ];    // ties at v (worst case all)
    __shared__ int      wave_sum[4];
    __shared__ int      s_selbin, s_K, s_ecnt;

    const int b    = blockIdx.x;
    const int tid  = threadIdx.x;
    const int wid  = tid >> 6;

    for (int q = tid; q < NQ; q += NTM)
        su[q] = __float_as_uint(scores[b * NQ + q]);
    for (int i = tid; i < FH * 4; i += NTM) cov[i] = 0u;
    if (tid == 0) s_ecnt = 0;

    // ---- byte-wise radix descent with parallel suffix-scan bin select ----
    unsigned prefix = 0, pmask = 0;
    int K = TOPK;
#pragma unroll
    for (int p = 0; p < 4; ++p) {
        const int shift = 24 - 8 * p;
        for (int i = tid; i < 8 * 256; i += NTM) ((int*)hist)[i] = 0;
        __syncthreads();
        for (int q = tid; q < NQ; q += NTM) {
            unsigned u = su[q];
            if ((u & pmask) == prefix)
                atomicAdd(&hist[wid][(u >> shift) & 0xFF], 1);
        }
        __syncthreads();
        // first 256 threads: suffix scan over bins (reversed index = prefix scan)
        int x = 0, hx = 0, bin = 0;
        if (tid < 256) {
            bin = 255 - tid;
            hx = hist[0][bin] + hist[1][bin] + hist[2][bin] + hist[3][bin] +
                 hist[4][bin] + hist[5][bin] + hist[6][bin] + hist[7][bin];
            x = hx;
#pragma unroll
            for (int off = 1; off < 64; off <<= 1) {
                int y = __shfl_up(x, off, 64);
                if ((tid & 63) >= off) x += y;
            }
            if ((tid & 63) == 63) wave_sum[tid >> 6] = x;
        }
        __syncthreads();
        if (tid < 256) {
            int w = tid >> 6;
            for (int j = 0; j < w; ++j) x += wave_sum[j];
            int ge_incl = x;          // count of prefix-matching su with byte >= bin
            int ge_excl = x - hx;     // count with byte > bin
            if (ge_incl >= K && ge_excl < K) {
                s_selbin = bin;
                s_K      = K - ge_excl;
            }
        }
        __syncthreads();
        prefix |= ((unsigned)s_selbin) << shift;
        pmask  |= (0xFFu << shift);
        K = s_K;
        __syncthreads();
    }
    const unsigned v      = prefix;  // exact bits of TOPK-th largest
    const int      e_take = K;       // how many su==v to take (smallest indices)

    const float s0 = (float)vfs[2 * b];      // reference scales x by vfs[:,0]
    const float s1 = (float)vfs[2 * b + 1];  // and y by vfs[:,1] (quirk replicated)

    // ---- selection + raster (atomicOr; scattered addresses, light conflicts) ----
    for (int q = tid; q < NQ; q += NTM) {
        unsigned u = su[q];
        if (u > v) {
            float4 c4 = coord[(size_t)b * NQ + q];
            float x1 = c4.x - 0.5f * c4.z, y1 = c4.y - 0.5f * c4.w;
            float x2 = c4.x + 0.5f * c4.z, y2 = c4.y + 0.5f * c4.w;
            int lx = (int)floorf(x1 * s0), ly = (int)floorf(y1 * s1);
            int rx = (int)floorf(x2 * s0), ry = (int)floorf(y2 * s1);
            int h0 = ly > 0 ? ly : 0, h1 = ry < FH ? ry : FH;
            int w0 = lx > 0 ? lx : 0, w1 = rx < FW ? rx : FW;
            if (h0 < h1 && w0 < w1) {
                unsigned m[4];
#pragma unroll
                for (int j = 0; j < 4; ++j) {
                    int lo = w0 - 32 * j; lo = lo < 0 ? 0 : lo;
                    int hi = w1 - 32 * j; hi = hi > 32 ? 32 : hi;
                    unsigned mm = 0u;
                    if (hi > lo) {
                        unsigned top = (hi >= 32) ? 0xFFFFFFFFu : ((1u << hi) - 1u);
                        unsigned bot = (lo <= 0) ? 0u : ((1u << lo) - 1u);
                        mm = top & ~bot;
                    }
                    m[j] = mm;
                }
                for (int h = h0; h < h1; ++h) {
#pragma unroll
                    for (int j = 0; j < 4; ++j)
                        if (m[j]) atomicOr(&cov[h * 4 + j], m[j]);
                }
            }
        } else if (u == v) {
            int i = atomicAdd(&s_ecnt, 1);
            eqlist[i] = q;
        }
    }
    __syncthreads();

    // ---- stable tie-break: take e_take smallest-index ties ----
    const int E = s_ecnt;
    for (int i = tid; i < E; i += NTM) {
        int q = eqlist[i];
        int r = 0;
        for (int j = 0; j < E; ++j) r += (eqlist[j] < q) ? 1 : 0;
        if (r < e_take) {
            float4 c4 = coord[(size_t)b * NQ + q];
            float x1 = c4.x - 0.5f * c4.z, y1 = c4.y - 0.5f * c4.w;
            float x2 = c4.x + 0.5f * c4.z, y2 = c4.y + 0.5f * c4.w;
            int lx = (int)floorf(x1 * s0), ly = (int)floorf(y1 * s1);
            int rx = (int)floorf(x2 * s0), ry = (int)floorf(y2 * s1);
            int h0 = ly > 0 ? ly : 0, h1 = ry < FH ? ry : FH;
            int w0 = lx > 0 ? lx : 0, w1 = rx < FW ? rx : FW;
            if (h0 < h1 && w0 < w1) {
                for (int h = h0; h < h1; ++h) {
#pragma unroll
                    for (int j = 0; j < 4; ++j) {
                        int lo = w0 - 32 * j; lo = lo < 0 ? 0 : lo;
                        int hi = w1 - 32 * j; hi = hi > 32 ? 32 : hi;
                        if (hi > lo) {
                            unsigned top = (hi >= 32) ? 0xFFFFFFFFu : ((1u << hi) - 1u);
                            unsigned bot = (lo <= 0) ? 0u : ((1u << lo) - 1u);
                            atomicOr(&cov[h * 4 + j], top & ~bot);
                        }
                    }
                }
            }
        }
    }
    __syncthreads();

    // ---- emit mask fused with padding (recomputed from vfs) ----
    const int iv0 = vfs[2 * b], iv1 = vfs[2 * b + 1];
    for (int idx = tid; idx < FH * FW; idx += NTM) {
        int h = idx / FW;
        int w = idx - h * FW;
        bool covered = (cov[h * 4 + (w >> 5)] >> (w & 31)) & 1u;
        bool pad = (h >= iv0) || (w >= iv1);
        out[(size_t)b * (FH * FW) + idx] = (covered && !pad) ? 0.0f : -1e20f;
    }
}

extern "C" void kernel_launch(void* const* d_in, const int* in_sizes, int n_in,
                              void* d_out, int out_size, void* d_ws, size_t ws_size,
                              hipStream_t stream) {
    const float4* coord = (const float4*)d_in[0];  // (BS, NQ, 4) f32
    const float*  cls   = (const float*)d_in[1];   // (BS, NQ, NC) f32
    const int*    vfs   = (const int*)d_in[2];     // (BS, 2) i32
    // d_in[3] (padding_mask) ignored — recomputed from vfs.
    float* scores = (float*)d_ws;                  // BS*NQ floats
    float* out    = (float*)d_out;

    const int rows = BS * NQ;                      // 192000
    scores_kernel<<<rows / 16, 256, 0, stream>>>((const float4*)cls, scores);
    mask_kernel<<<BS, NTM, 0, stream>>>(coord, vfs, scores, out);
}